// Round 6
// baseline (51.368 us; speedup 1.0000x reference)
//
#include <hip/hip_runtime.h>

#define MARGIN 0.1f
#define B 512
#define P 4
#define N 64
#define D 1024
#define NV (P + N)   // 68 score vectors per batch row

// One block per batch row b. 1024 threads = 16 waves -> 32 waves/CU at
// 2 blocks/CU. Single compute dispatch: the 512th-arriving block reduces
// the per-row partials (ticket is zeroed by a memset node each call).
__global__ __launch_bounds__(1024) void loss_kernel(
    const float* __restrict__ q,     // [B, D]
    const float* __restrict__ pos,   // [B, P, D]
    const float* __restrict__ neg,   // [B, N, D]
    float* __restrict__ partial,     // [B]  (d_ws, fully rewritten per call)
    unsigned* __restrict__ ticket,   // [1]  (d_ws, memset to 0 per call)
    float* __restrict__ out)         // [1]
{
    const int b    = blockIdx.x;
    const int tid  = threadIdx.x;
    const int lane = tid & 63;
    const int wave = tid >> 6;       // 0..15

    // Each lane keeps 16 query floats (4 x float4), coalesced 1KB/load.
    // All 16 waves read the same 4KB row -> L1-resident after first wave.
    const float4* q4 = (const float4*)(q + (size_t)b * D);
    float4 qv[4];
#pragma unroll
    for (int i = 0; i < 4; ++i) qv[i] = q4[i * 64 + lane];

    __shared__ float scores[NV];     // [0..3]=pos, [4..67]=neg

    // 68 vectors over 16 waves: waves 0-3 do 5, waves 4-15 do 4.
    for (int v = wave; v < NV; v += 16) {
        const float* vec = (v < P)
            ? (pos + ((size_t)b * P + v) * D)
            : (neg + ((size_t)b * N + (v - P)) * D);
        const float4* v4 = (const float4*)vec;
        float acc = 0.0f;
#pragma unroll
        for (int i = 0; i < 4; ++i) {
            float4 x = v4[i * 64 + lane];
            acc += qv[i].x * x.x + qv[i].y * x.y + qv[i].z * x.z + qv[i].w * x.w;
        }
#pragma unroll
        for (int off = 32; off > 0; off >>= 1)
            acc += __shfl_down(acc, off, 64);
        if (lane == 0) scores[v] = acc;
    }
    __syncthreads();

    // Pairwise: 4*64 = 256 pairs on waves 0..3 (one pair per thread).
    __shared__ float wsum[4];
    if (wave < 4) {
        float ps  = scores[wave];            // pos index
        float ns  = scores[P + lane];        // neg index
        float val = fmaxf(MARGIN - ps + ns, 0.0f);
#pragma unroll
        for (int off = 32; off > 0; off >>= 1)
            val += __shfl_down(val, off, 64);
        if (lane == 0) wsum[wave] = val;
    }
    __syncthreads();

    // Publish partial (release), take ticket (acq_rel, agent scope ->
    // XCD-coherent). Ticket starts at 0 each call (memset node), so
    // old+1 == B identifies the true last arrival.
    __shared__ int lastFlag;
    if (tid == 0) {
        float s = wsum[0] + wsum[1] + wsum[2] + wsum[3];
        __hip_atomic_store(&partial[b], s, __ATOMIC_RELEASE,
                           __HIP_MEMORY_SCOPE_AGENT);
        unsigned old = __hip_atomic_fetch_add(ticket, 1u, __ATOMIC_ACQ_REL,
                                              __HIP_MEMORY_SCOPE_AGENT);
        lastFlag = (old + 1u == (unsigned)B);
    }
    __syncthreads();

    // Last block: wave 0 reduces the 512 partials and writes the mean.
    // The acq_rel fetch_add above synchronized with every other block's
    // release store, so relaxed agent loads see all partials.
    if (lastFlag && wave == 0) {
        float v = 0.0f;
#pragma unroll
        for (int k = 0; k < 8; ++k)
            v += __hip_atomic_load(&partial[lane + 64 * k], __ATOMIC_RELAXED,
                                   __HIP_MEMORY_SCOPE_AGENT);
#pragma unroll
        for (int off = 32; off > 0; off >>= 1)
            v += __shfl_down(v, off, 64);
        if (lane == 0)
            out[0] = v / (float)(B * P * N);
    }
}

extern "C" void kernel_launch(void* const* d_in, const int* in_sizes, int n_in,
                              void* d_out, int out_size, void* d_ws, size_t ws_size,
                              hipStream_t stream) {
    const float* q   = (const float*)d_in[0];   // [512,1024]
    const float* pos = (const float*)d_in[1];   // [512,4,1024]
    const float* neg = (const float*)d_in[2];   // [512,64,1024]
    float* out       = (float*)d_out;
    float* partial   = (float*)d_ws;            // 512 floats
    unsigned* ticket = (unsigned*)((char*)d_ws + B * sizeof(float));

    // Zero the ticket every call (graph-capturable memset node) so the
    // last-arrival test is exact regardless of d_ws poison.
    hipMemsetAsync(ticket, 0, sizeof(unsigned), stream);
    loss_kernel<<<B, 1024, 0, stream>>>(q, pos, neg, partial, ticket, out);
}

// Round 8
// 26.468 us; speedup vs baseline: 1.9408x; 1.9408x over previous
//
#include <hip/hip_runtime.h>

#define MARGIN 0.1f
#define B 512
#define P 4
#define N 64
#define D 1024
#define NV (P + N)   // 68 score vectors per batch row

// Native vector type for nontemporal builtins (HIP_vector_type is rejected).
typedef float f32x4 __attribute__((ext_vector_type(4)));

// Non-temporal 16B load: streaming data with zero reuse -> don't
// allocate in caches (emits global_load_dwordx4 ... nt).
__device__ __forceinline__ f32x4 nt_load4(const float* p) {
    return __builtin_nontemporal_load((const f32x4*)p);
}

// One block per batch row b. 1024 threads = 16 waves -> 32 waves/CU at
// 2 blocks/CU (known-good round-2 structure + NT streaming loads).
__global__ __launch_bounds__(1024) void scores_kernel(
    const float* __restrict__ q,     // [B, D]
    const float* __restrict__ pos,   // [B, P, D]
    const float* __restrict__ neg,   // [B, N, D]
    float* __restrict__ partial)     // [B]
{
    const int b    = blockIdx.x;
    const int tid  = threadIdx.x;
    const int lane = tid & 63;
    const int wave = tid >> 6;       // 0..15

    // Each lane keeps 16 query floats (4 x float4), coalesced 1KB/load.
    // All 16 waves read the same 4KB row -> keep CACHED (L1 reuse).
    const float4* q4 = (const float4*)(q + (size_t)b * D);
    float4 qv[4];
#pragma unroll
    for (int i = 0; i < 4; ++i) qv[i] = q4[i * 64 + lane];

    __shared__ float scores[NV];     // [0..3]=pos, [4..67]=neg

    // 68 vectors over 16 waves: waves 0-3 do 5, waves 4-15 do 4.
    for (int v = wave; v < NV; v += 16) {
        const float* vec = (v < P)
            ? (pos + ((size_t)b * P + v) * D)
            : (neg + ((size_t)b * N + (v - P)) * D);
        float acc = 0.0f;
#pragma unroll
        for (int i = 0; i < 4; ++i) {
            f32x4 x = nt_load4(vec + (i * 64 + lane) * 4);
            acc += qv[i].x * x.x + qv[i].y * x.y + qv[i].z * x.z + qv[i].w * x.w;
        }
#pragma unroll
        for (int off = 32; off > 0; off >>= 1)
            acc += __shfl_down(acc, off, 64);
        if (lane == 0) scores[v] = acc;
    }
    __syncthreads();

    // Pairwise: 4*64 = 256 pairs on waves 0..3 (one pair per thread).
    __shared__ float wsum[4];
    if (wave < 4) {
        float ps  = scores[wave];            // pos index
        float ns  = scores[P + lane];        // neg index
        float val = fmaxf(MARGIN - ps + ns, 0.0f);
#pragma unroll
        for (int off = 32; off > 0; off >>= 1)
            val += __shfl_down(val, off, 64);
        if (lane == 0) wsum[wave] = val;
    }
    __syncthreads();
    if (tid == 0)
        partial[b] = wsum[0] + wsum[1] + wsum[2] + wsum[3];
}

// Deterministic final reduction: one wave, 8 partials per lane, no syncs.
__global__ __launch_bounds__(64) void finalize_kernel(
    const float* __restrict__ partial, float* __restrict__ out)
{
    const int lane = threadIdx.x;
    float v = 0.0f;
#pragma unroll
    for (int k = 0; k < 8; ++k)
        v += partial[lane + 64 * k];
#pragma unroll
    for (int off = 32; off > 0; off >>= 1)
        v += __shfl_down(v, off, 64);
    if (lane == 0)
        out[0] = v / (float)(B * P * N);
}

extern "C" void kernel_launch(void* const* d_in, const int* in_sizes, int n_in,
                              void* d_out, int out_size, void* d_ws, size_t ws_size,
                              hipStream_t stream) {
    const float* q   = (const float*)d_in[0];   // [512,1024]
    const float* pos = (const float*)d_in[1];   // [512,4,1024]
    const float* neg = (const float*)d_in[2];   // [512,64,1024]
    float* out       = (float*)d_out;
    float* partial   = (float*)d_ws;            // 512 floats

    scores_kernel<<<B, 1024, 0, stream>>>(q, pos, neg, partial);
    finalize_kernel<<<1, 64, 0, stream>>>(partial, out);
}